// Round 1
// baseline (554.833 us; speedup 1.0000x reference)
//
#include <hip/hip_runtime.h>
#include <hip/hip_bf16.h>

namespace {

constexpr int N_NODES = 100000;
constexpr int N_EDGES = 3200000;
constexpr int D = 16;
constexpr int H = 64;
constexpr int C = 10;
constexpr int L = 2;
constexpr int BLK = 256;

__global__ void k_deg_init(float* __restrict__ deg) {
  int i = blockIdx.x * BLK + threadIdx.x;
  if (i < N_NODES) deg[i] = 1.0f;  // self-loop weight (fill_value = 1)
}

__global__ void k_deg_edges(const int* __restrict__ col, const float* __restrict__ ew,
                            float* __restrict__ deg) {
  int stride = gridDim.x * BLK;
  for (int i = blockIdx.x * BLK + threadIdx.x; i < N_EDGES; i += stride)
    atomicAdd(&deg[col[i]], ew[i]);
}

__global__ void k_dinv(const float* __restrict__ deg, float* __restrict__ dinv) {
  int i = blockIdx.x * BLK + threadIdx.x;
  if (i < N_NODES) {
    float d = deg[i];
    dinv[i] = d > 0.f ? rsqrtf(fmaxf(d, 1e-30f)) : 0.f;
  }
}

// out[v,:] = h[v,:] @ W^T ; agg[v,:] = dinv[v]^2 * out[v,:]  (self-loop term)
__global__ void k_lin(const float* __restrict__ hin, const float* __restrict__ W,
                      const float* __restrict__ dinv, float* __restrict__ out,
                      float* __restrict__ agg) {
  __shared__ float sW[D * D];  // 256 floats, BLK==256: one element per thread
  sW[threadIdx.x] = W[threadIdx.x];
  __syncthreads();
  int v = blockIdx.x * BLK + threadIdx.x;
  if (v >= N_NODES) return;
  float hv[D];
  const float4* hp = reinterpret_cast<const float4*>(hin + (size_t)v * D);
#pragma unroll
  for (int c = 0; c < 4; ++c) {
    float4 t = hp[c];
    hv[4 * c + 0] = t.x; hv[4 * c + 1] = t.y;
    hv[4 * c + 2] = t.z; hv[4 * c + 3] = t.w;
  }
  float dv = dinv[v];
  float dv2 = dv * dv;
  float4* op = reinterpret_cast<float4*>(out + (size_t)v * D);
  float4* ap = reinterpret_cast<float4*>(agg + (size_t)v * D);
#pragma unroll
  for (int jc = 0; jc < 4; ++jc) {
    float o[4];
#pragma unroll
    for (int jj = 0; jj < 4; ++jj) {
      int j = jc * 4 + jj;
      float s = 0.f;
#pragma unroll
      for (int k = 0; k < D; ++k) s += hv[k] * sW[j * D + k];
      o[jj] = s;
    }
    float4 t = make_float4(o[0], o[1], o[2], o[3]);
    op[jc] = t;
    ap[jc] = make_float4(t.x * dv2, t.y * dv2, t.z * dv2, t.w * dv2);
  }
}

// agg[col[e], l] += dinv[row]*ew*dinv[col] * out[row[e], l]
// layout: gid = e*16 + l -> each 16-lane group gathers one 64B line
__global__ void k_edge(const int* __restrict__ row, const int* __restrict__ col,
                       const float* __restrict__ ew, const float* __restrict__ dinv,
                       const float* __restrict__ out, float* __restrict__ agg) {
  const int total = N_EDGES * D;  // 51.2M, fits int
  int stride = gridDim.x * BLK;
  for (int g = blockIdx.x * BLK + threadIdx.x; g < total; g += stride) {
    int e = g >> 4;
    int l = g & 15;
    int r = row[e];
    int c = col[e];
    float nv = dinv[r] * ew[e] * dinv[c];
    atomicAdd(&agg[c * D + l], nv * out[r * D + l]);
  }
}

// h[v,:] = LayerNorm(LeakyReLU(tanh(agg @ Wn^T + nb) + cb)) * g + b
__global__ void k_update(const float* __restrict__ agg, const float* __restrict__ Wn,
                         const float* __restrict__ nb, const float* __restrict__ cb,
                         const float* __restrict__ lg, const float* __restrict__ lb,
                         float* __restrict__ h) {
  __shared__ float sW[D * D];
  __shared__ float snb[D], scb[D], slg[D], slb[D];
  sW[threadIdx.x] = Wn[threadIdx.x];
  if (threadIdx.x < D) {
    snb[threadIdx.x] = nb[threadIdx.x];
    scb[threadIdx.x] = cb[threadIdx.x];
    slg[threadIdx.x] = lg[threadIdx.x];
    slb[threadIdx.x] = lb[threadIdx.x];
  }
  __syncthreads();
  int v = blockIdx.x * BLK + threadIdx.x;
  if (v >= N_NODES) return;
  float a[D];
  const float4* ap = reinterpret_cast<const float4*>(agg + (size_t)v * D);
#pragma unroll
  for (int c = 0; c < 4; ++c) {
    float4 t = ap[c];
    a[4 * c + 0] = t.x; a[4 * c + 1] = t.y;
    a[4 * c + 2] = t.z; a[4 * c + 3] = t.w;
  }
  float t[D];
#pragma unroll
  for (int j = 0; j < D; ++j) {
    float s = snb[j];
#pragma unroll
    for (int k = 0; k < D; ++k) s += a[k] * sW[j * D + k];
    float u = tanhf(s) + scb[j];
    t[j] = u > 0.f ? u : 0.2f * u;  // LeakyReLU(0.2)
  }
  float mu = 0.f;
#pragma unroll
  for (int j = 0; j < D; ++j) mu += t[j];
  mu *= (1.0f / D);
  float var = 0.f;
#pragma unroll
  for (int j = 0; j < D; ++j) { float d0 = t[j] - mu; var += d0 * d0; }
  var *= (1.0f / D);
  float inv = rsqrtf(var + 1e-5f);
  float4* hp = reinterpret_cast<float4*>(h + (size_t)v * D);
#pragma unroll
  for (int c = 0; c < 4; ++c) {
    float o[4];
#pragma unroll
    for (int jj = 0; jj < 4; ++jj) {
      int j = c * 4 + jj;
      o[jj] = (t[j] - mu) * inv * slg[j] + slb[j];
    }
    hp[c] = make_float4(o[0], o[1], o[2], o[3]);
  }
}

// out[v,:] = relu(h @ w1^T + b1) @ w2^T + b2
__global__ void k_cls(const float* __restrict__ h, const float* __restrict__ w1,
                      const float* __restrict__ b1, const float* __restrict__ w2,
                      const float* __restrict__ b2, float* __restrict__ out) {
  __shared__ float sw1[H * D];   // 1024
  __shared__ float sb1[H];
  __shared__ float sw2[C * H];   // 640
  __shared__ float sb2[C];
  for (int i = threadIdx.x; i < H * D; i += BLK) sw1[i] = w1[i];
  for (int i = threadIdx.x; i < H; i += BLK) sb1[i] = b1[i];
  for (int i = threadIdx.x; i < C * H; i += BLK) sw2[i] = w2[i];
  for (int i = threadIdx.x; i < C; i += BLK) sb2[i] = b2[i];
  __syncthreads();
  int v = blockIdx.x * BLK + threadIdx.x;
  if (v >= N_NODES) return;
  float hv[D];
  const float4* hp = reinterpret_cast<const float4*>(h + (size_t)v * D);
#pragma unroll
  for (int c = 0; c < 4; ++c) {
    float4 t = hp[c];
    hv[4 * c + 0] = t.x; hv[4 * c + 1] = t.y;
    hv[4 * c + 2] = t.z; hv[4 * c + 3] = t.w;
  }
  float oc[C];
#pragma unroll
  for (int c = 0; c < C; ++c) oc[c] = sb2[c];
#pragma unroll
  for (int j = 0; j < H; ++j) {
    float s = sb1[j];
#pragma unroll
    for (int k = 0; k < D; ++k) s += hv[k] * sw1[j * D + k];
    s = fmaxf(s, 0.f);
#pragma unroll
    for (int c = 0; c < C; ++c) oc[c] += s * sw2[c * H + j];
  }
#pragma unroll
  for (int c = 0; c < C; ++c) out[(size_t)v * C + c] = oc[c];
}

}  // namespace

extern "C" void kernel_launch(void* const* d_in, const int* in_sizes, int n_in,
                              void* d_out, int out_size, void* d_ws, size_t ws_size,
                              hipStream_t stream) {
  const float* x         = (const float*)d_in[0];
  const int*   edge_idx  = (const int*)d_in[1];   // [2, E]
  const float* edge_attr = (const float*)d_in[2];
  // d_in[3] = batch (unused: single graph, no pooling in reference)
  const float* lin_w  = (const float*)d_in[4];
  const float* conv_b = (const float*)d_in[5];
  const float* node_w = (const float*)d_in[6];
  const float* node_b = (const float*)d_in[7];
  const float* ln_g   = (const float*)d_in[8];
  const float* ln_b   = (const float*)d_in[9];
  const float* w1     = (const float*)d_in[10];
  const float* b1     = (const float*)d_in[11];
  const float* w2     = (const float*)d_in[12];
  const float* b2     = (const float*)d_in[13];
  float* out = (float*)d_out;

  const int* row = edge_idx;            // source
  const int* col = edge_idx + N_EDGES;  // target

  // workspace layout (floats): deg[N] | dinv[N] | buf_out[N*D] | agg[N*D] | h[N*D]
  float* ws      = (float*)d_ws;
  float* deg     = ws;                      ws += N_NODES;
  float* dinv    = ws;                      ws += N_NODES;
  float* buf_out = ws;                      ws += (size_t)N_NODES * D;
  float* agg     = ws;                      ws += (size_t)N_NODES * D;
  float* hbuf    = ws;                      ws += (size_t)N_NODES * D;

  const int nbN = (N_NODES + BLK - 1) / BLK;          // 391
  const int nbE = 4096;                               // grid-stride over E
  const int nbEL = 8192;                              // grid-stride over E*16

  k_deg_init<<<nbN, BLK, 0, stream>>>(deg);
  k_deg_edges<<<nbE, BLK, 0, stream>>>(col, edge_attr, deg);
  k_dinv<<<nbN, BLK, 0, stream>>>(deg, dinv);

  for (int i = 0; i < L; ++i) {
    const float* hin = (i == 0) ? x : hbuf;
    k_lin<<<nbN, BLK, 0, stream>>>(hin, lin_w + i * D * D, dinv, buf_out, agg);
    k_edge<<<nbEL, BLK, 0, stream>>>(row, col, edge_attr, dinv, buf_out, agg);
    k_update<<<nbN, BLK, 0, stream>>>(agg, node_w + i * D * D, node_b + i * D,
                                      conv_b + i * D, ln_g + i * D, ln_b + i * D, hbuf);
  }
  k_cls<<<nbN, BLK, 0, stream>>>(hbuf, w1, b1, w2, b2, out);
}